// Round 2
// baseline (383.405 us; speedup 1.0000x reference)
//
#include <hip/hip_runtime.h>

// PWC-Net correlation: out[b, dy*9+dx, y, x] =
//   (1/C) * sum_c first[b,c,y,x] * second[b,c, y+dy-4, x+dx-4]  (zero-padded)
// B=8, C=128, H=W=128.
//
// Round 7: attack the staging wall (the round0/round1 invariant: ~490-590MB
// staged through 120 DMA instrs per CU-chunk with a vmcnt(0) drain per chunk
// = ~4.6TB/s effective = the 107us floor).
//  - ONE 9-wave block per (b,y0) tile: all 9 dy share a single second tile
//    (12 rows) and a single first tile. Staged bytes 490MB -> 268MB; DMA
//    instrs per CU-chunk 120 -> 64.
//  - Depth-2 prefetch over 3 LDS buffers, raw s_barrier + per-wave counted
//    vmcnt(8): loads stay in flight across the barrier; no vmcnt(0) in the
//    main loop. OOB rows DMA to a scratch sink so counts stay constant.
//  - Conflict-free reads: WP=132 + yi=lane&3 / xt=lane>>2 remap -> b128
//    start banks 4yi+8(xt&3), each 4-aligned bank exactly 2x per 16-lane
//    group (2-way is free).
//  - XCD swizzle: 256 blocks = 8 XCDs x 32; each XCD owns one batch b.

#define B  8
#define C  128
#define H  128
#define W  128
#define CC 4
#define YB 4
#define XT 8
#define NW 9
#define NTHR (NW * 64)         // 576
#define NCHUNK (C / CC)        // 32
#define SROWS 12               // second rows y0-4 .. y0+7, shared by all dy
#define WP (W + 4)             // 132 floats = 528B row stride (16B-aligned)
#define NBUF 3
#define CHSTRIDE (CC * H * W)  // 65536 floats per chunk step

typedef const void __attribute__((address_space(1)))* gvp;
typedef void __attribute__((address_space(3)))* lvp;

__device__ __forceinline__ void dma16(const float* g, float* l) {
    __builtin_amdgcn_global_load_lds((gvp)g, (lvp)l, 16, 0, 0);
}

__global__ __launch_bounds__(NTHR) __attribute__((amdgpu_waves_per_eu(3)))
void ModuleCorrelation_41970420416706_kernel(const float* __restrict__ first,
                                             const float* __restrict__ second,
                                             float* __restrict__ out) {
    __shared__ __align__(16) float sA[NBUF][CC][YB][WP];     // 24.75 KiB
    __shared__ __align__(16) float sS[NBUF][CC][SROWS][WP];  // 74.25 KiB
    __shared__ __align__(16) float scratch[W];               // OOB DMA sink

    // ---- XCD swizzle: 256 blocks = 8 XCDs x 32; XCD k gets batch b=k ----
    const int phys = blockIdx.x;
    const int li   = (phys & 7) * 32 + (phys >> 3);   // bijective, 256=8*32
    const int b    = li >> 5;
    const int y0   = (li & 31) * YB;

    const int t    = threadIdx.x;
    const int w    = t >> 6;                 // wave = dy in [0,9)
    const int lane = t & 63;
    const int yi   = lane & 3;               // row-fast lane map: spreads banks
    const int xt   = lane >> 2;              // 0..15
    const int x0   = xt * XT;

    const float* firstB  = first  + (size_t)b * C * H * W;
    const float* secondB = second + (size_t)b * C * H * W;

    // ---- pre-zero OOB second rows (never DMA'd: staging redirects them) ----
    for (int idx = t; idx < NBUF * CC * SROWS; idx += NTHR) {
        const int rr = idx % SROWS;
        const int ys = y0 - 4 + rr;
        if (ys < 0 || ys >= H) {
            const int bf = idx / (CC * SROWS);
            const int c  = (idx / SROWS) % CC;
            for (int x = 0; x < WP; x += 4)
                *(float4*)&sS[bf][c][rr][x] = make_float4(0.f, 0.f, 0.f, 0.f);
        }
    }

    // ---- staging: waves 0..7 issue exactly 8 half-wave row DMAs each ----
    // rows 0..15 = first (c=idx>>2, r=idx&3); rows 16..63 = second (48 rows).
    // OOB second rows load a clamped source into scratch (count-preserving).
    auto stage = [&](int buf, int chunk) {
        if (w >= 8 || lane >= 32) return;
        const int off = chunk * CHSTRIDE;
#pragma unroll
        for (int i = 0; i < 8; ++i) {
            const int idx = w * 8 + i;               // wave-uniform
            if (idx < 16) {
                const int c = idx >> 2, r = idx & 3;
                dma16(firstB + off + (c * H + y0 + r) * W + lane * 4,
                      &sA[buf][c][r][0]);
            } else {
                const int j   = idx - 16;
                const int c   = j / SROWS;
                const int rr  = j % SROWS;
                const int ys  = y0 - 4 + rr;
                const int ysc = ys < 0 ? 0 : (ys > H - 1 ? H - 1 : ys);
                float* dst = (ys == ysc) ? &sS[buf][c][rr][0] : &scratch[0];
                dma16(secondB + off + (c * H + ysc) * W + lane * 4, dst);
            }
        }
    };

    float acc[9][XT];
#pragma unroll
    for (int dx = 0; dx < 9; ++dx)
#pragma unroll
        for (int j = 0; j < XT; ++j) acc[dx][j] = 0.f;

    // ---- prologue: zeros visible, stage chunks 0 and 1 ----
    asm volatile("s_waitcnt lgkmcnt(0)" ::: "memory");
    stage(0, 0);
    stage(1, 1);
    if (w < 8) asm volatile("s_waitcnt vmcnt(8)" ::: "memory");  // chunk0 landed
    asm volatile("s_barrier" ::: "memory");

    const bool edgeL = (xt == 0);
    const bool edgeR = (xt == 15);
    const int offA = edgeL ? 0 : x0 - 4;     // clamped aligned read, masked below
    const int offC = edgeR ? x0 + 4 : x0 + 8;
    const int fOff = yi * WP + x0;
    const int sOff = (yi + w) * WP;          // rr = yi + dy

    int bc = 0, bs = 2;                      // compute buf, next stage buf
    for (int k = 0; k < NCHUNK; ++k) {
        const float* sF  = &sA[bc][0][0][0];
        const float* sSb = &sS[bc][0][0][0];
#pragma unroll
        for (int c = 0; c < CC; ++c) {
            const float4 f0 = *(const float4*)(sF + c * (YB * WP) + fOff);
            const float4 f1 = *(const float4*)(sF + c * (YB * WP) + fOff + 4);
            const float* sr = sSb + c * (SROWS * WP) + sOff;
            float4 A        = *(const float4*)(sr + offA);
            const float4 B0 = *(const float4*)(sr + x0);
            const float4 B1 = *(const float4*)(sr + x0 + 4);
            float4 Cv       = *(const float4*)(sr + offC);
            if (edgeL) { A.x = 0.f; A.y = 0.f; A.z = 0.f; A.w = 0.f; }
            if (edgeR) { Cv.x = 0.f; Cv.y = 0.f; Cv.z = 0.f; Cv.w = 0.f; }
            const float s[16] = {A.x,  A.y,  A.z,  A.w,
                                 B0.x, B0.y, B0.z, B0.w,
                                 B1.x, B1.y, B1.z, B1.w,
                                 Cv.x, Cv.y, Cv.z, Cv.w};
            const float ff[8] = {f0.x, f0.y, f0.z, f0.w,
                                 f1.x, f1.y, f1.z, f1.w};
#pragma unroll
            for (int dx = 0; dx < 9; ++dx)
#pragma unroll
                for (int j = 0; j < XT; ++j)
                    acc[dx][j] += ff[j] * s[dx + j];
        }
        // one barrier per chunk; counted vmcnt keeps 2 stages in flight.
        if (k + 2 < NCHUNK) {
            stage(bs, k + 2);
            if (w < 8) asm volatile("s_waitcnt vmcnt(8)" ::: "memory");
        } else {
            asm volatile("s_waitcnt vmcnt(0)" ::: "memory");
        }
        asm volatile("s_waitcnt lgkmcnt(0)" ::: "memory");  // own LDS reads done
        asm volatile("s_barrier" ::: "memory");
        bc = (bc + 1 == NBUF) ? 0 : bc + 1;
        bs = (bs + 1 == NBUF) ? 0 : bs + 1;
    }

    // ---- epilogue ----
    const float scale = 1.0f / (float)C;
    const int dy = w;
    const int yOut = y0 + yi;
#pragma unroll
    for (int dx = 0; dx < 9; ++dx) {
        const int tc = dy * 9 + dx;
        float* op = &out[((b * 81 + tc) * H + yOut) * W + x0];
        float4 o0, o1;
        o0.x = acc[dx][0] * scale;
        o0.y = acc[dx][1] * scale;
        o0.z = acc[dx][2] * scale;
        o0.w = acc[dx][3] * scale;
        o1.x = acc[dx][4] * scale;
        o1.y = acc[dx][5] * scale;
        o1.z = acc[dx][6] * scale;
        o1.w = acc[dx][7] * scale;
        *(float4*)op       = o0;
        *(float4*)(op + 4) = o1;
    }
}

extern "C" void kernel_launch(void* const* d_in, const int* in_sizes, int n_in,
                              void* d_out, int out_size, void* d_ws, size_t ws_size,
                              hipStream_t stream) {
    const float* first  = (const float*)d_in[0];
    const float* second = (const float*)d_in[1];
    float* out = (float*)d_out;

    dim3 grid(B * (H / YB));   // 256 blocks = 8 XCDs x 32 = 1 per CU
    dim3 block(NTHR);          // 576 threads = 9 waves (one dy each)
    ModuleCorrelation_41970420416706_kernel<<<grid, block, 0, stream>>>(first, second, out);
}

// Round 3
// 195.086 us; speedup vs baseline: 1.9653x; 1.9653x over previous
//
#include <hip/hip_runtime.h>

// PWC-Net correlation: out[b, dy*9+dx, y, x] =
//   (1/C) * sum_c first[b,c,y,x] * second[b,c, y+dy-4, x+dx-4]  (zero-padded)
// B=8, C=128, H=W=128.
//
// Round 8: R1 kernel with ONE change — kill the per-chunk vmcnt(0) drain.
// R2's post-mortem: staged-bytes cut 2x made it 2.6x SLOWER (9-wave lockstep,
// 8-way conflicts from the lane remap, scattered 16B writes). R0==R1==107us
// despite FETCH 261->68MB: the shared invariant is the __syncthreads drain.
// Here: counted per-wave vmcnt(N) (N = own just-issued DMA count; 16 for the
// first-staging wave, 12 for second-staging waves) + two light s_barriers per
// chunk. Chunk k+1's DMAs stay in flight across the barrier and get a full
// chunk of compute to land. vmcnt -> barrier -> read ordering publishes all
// waves' rows. OOB rows: count-preserving redirect (clamped source -> LDS
// scratch sink), rows stay pre-zeroed. Everything else identical to R1
// (lane map yi=lane>>4/xt=lane&15, WP=132 padding, XCD swizzle, 3 blocks/CU).

#define B  8
#define C  128
#define H  128
#define W  128
#define CC 4
#define YB 4
#define XT 8
#define NTHR 192
#define NCHUNK (C / CC)        // 32
#define SROWS 6                // second rows per dy-group (yi 0..3 + w 0..2)
#define WP (W + 4)             // padded LDS row stride (floats)
#define CHSTRIDE (CC * H * W)  // 65536 floats per chunk step

typedef const void __attribute__((address_space(1)))* gvp;
typedef void __attribute__((address_space(3)))* lvp;

__device__ __forceinline__ void dma16(const float* g, float* l) {
    __builtin_amdgcn_global_load_lds((gvp)g, (lvp)l, 16, 0, 0);
}

__global__ __launch_bounds__(NTHR) __attribute__((amdgpu_waves_per_eu(3)))
void ModuleCorrelation_41970420416706_kernel(const float* __restrict__ first,
                                             const float* __restrict__ second,
                                             float* __restrict__ out) {
    __shared__ __align__(16) float sFirst[2][CC][YB][WP];     // 16.5 KiB
    __shared__ __align__(16) float sSec[2][CC][SROWS][WP];    // 24.75 KiB
    __shared__ __align__(16) float scratch[W];                // OOB DMA sink

    // ---- XCD swizzle: phys blocks round-robin XCDs; XCD k gets batch b=k ----
    const int phys = blockIdx.x;
    const int li   = (phys & 7) * 96 + (phys >> 3);   // 768 = 8*96, bijective
    const int b    = li / 96;
    const int rem  = li - b * 96;
    const int y0   = (rem / 3) * YB;
    const int dg   = rem - (rem / 3) * 3;    // dg fastest: siblings adjacent
    const int d0   = dg * 3;                 // dy group base: 0, 3, 6

    const int t    = threadIdx.x;
    const int w    = t >> 6;                 // wave = dy - d0, in [0,3)
    const int lane = t & 63;
    const int yi   = lane >> 4;              // 0..3
    const int xt   = lane & 15;              // 0..15
    const int x0   = xt * XT;                // 0,8,...,120

    const float* firstB  = first  + (size_t)b * C * H * W;
    const float* secondB = second + (size_t)b * C * H * W;

    // ---- pre-zero OOB second rows (never DMA'd: staging redirects them) ----
    for (int idx = t; idx < 2 * CC * SROWS; idx += NTHR) {    // 48 rows
        const int rr = idx % SROWS;
        const int ys = y0 + d0 - 4 + rr;
        if (ys < 0 || ys >= H) {
            const int bf = idx / (CC * SROWS);
            const int c  = (idx / SROWS) % CC;
            for (int x = 0; x < W; x += 4)
                *(float4*)&sSec[bf][c][rr][x] = make_float4(0.f, 0.f, 0.f, 0.f);
        }
    }

    // ---- staging: per-row half-wave DMAs (512B). wave2: 16 first rows;
    //      waves 0,1: 12 second rows each. OOB rows: clamped source ->
    //      scratch sink (count-preserving so counted vmcnt is exact). ----
    auto stage = [&](int buf, int chunk) {
        const int off = chunk * CHSTRIDE;
        if (w == 2) {
            if (lane < 32) {
#pragma unroll
                for (int i = 0; i < 16; ++i) {       // c = i>>2, row = i&3
                    const int c = i >> 2, r = i & 3;
                    dma16(firstB + off + (c * H + y0 + r) * W + lane * 4,
                          &sFirst[buf][c][r][0]);
                }
            }
        } else if (lane < 32) {
#pragma unroll
            for (int i = 0; i < 12; ++i) {
                const int c   = w * 2 + i / 6;       // wave-uniform
                const int rr  = i % 6;
                const int ys  = y0 + d0 - 4 + rr;
                const int ysc = ys < 0 ? 0 : (ys > H - 1 ? H - 1 : ys);
                float* dst = (ys == ysc) ? &sSec[buf][c][rr][0] : &scratch[0];
                dma16(secondB + off + (c * H + ysc) * W + lane * 4, dst);
            }
        }
    };

    float acc[9][XT];
#pragma unroll
    for (int dx = 0; dx < 9; ++dx)
#pragma unroll
        for (int j = 0; j < XT; ++j) acc[dx][j] = 0.f;

    // ---- prologue: stage chunk 0; zeros + own-issue ordering ----
    stage(0, 0);
    asm volatile("s_waitcnt lgkmcnt(0)" ::: "memory");   // zero-stores done

    const bool edgeL = (xt == 0);
    const bool edgeR = (xt == 15);
    const int offA = edgeL ? 0 : x0 - 4;      // clamped aligned read, masked below
    const int offC = edgeR ? x0 + 4 : x0 + 8;
    const int fOff = yi * WP + x0;
    const int sOff = (yi + w) * WP;           // rr = yi + w

    for (int k = 0; k < NCHUNK; ++k) {
        const int buf = k & 1;
        // A: issue next chunk (buf^1 is free: barrier F of iter k-1 passed)
        if (k + 1 < NCHUNK) {
            stage(buf ^ 1, k + 1);
            // B: wait for OWN chunk-k loads (the N just issued may remain)
            if (w == 2) asm volatile("s_waitcnt vmcnt(16)" ::: "memory");
            else        asm volatile("s_waitcnt vmcnt(12)" ::: "memory");
        } else {
            asm volatile("s_waitcnt vmcnt(0)" ::: "memory");
        }
        // C: publish — after this, ALL waves' chunk-k rows are in LDS
        asm volatile("s_barrier" ::: "memory");

        const float* sF  = &sFirst[buf][0][0][0];
        const float* sSb = &sSec[buf][0][0][0];
#pragma unroll
        for (int c = 0; c < CC; ++c) {
            const float4 f0 = *(const float4*)(sF + c * (YB * WP) + fOff);
            const float4 f1 = *(const float4*)(sF + c * (YB * WP) + fOff + 4);
            const float* sr = sSb + c * (SROWS * WP) + sOff;
            float4 A        = *(const float4*)(sr + offA);
            const float4 B0 = *(const float4*)(sr + x0);
            const float4 B1 = *(const float4*)(sr + x0 + 4);
            float4 Cv       = *(const float4*)(sr + offC);
            if (edgeL) { A.x = 0.f; A.y = 0.f; A.z = 0.f; A.w = 0.f; }
            if (edgeR) { Cv.x = 0.f; Cv.y = 0.f; Cv.z = 0.f; Cv.w = 0.f; }
            const float s[16] = {A.x,  A.y,  A.z,  A.w,
                                 B0.x, B0.y, B0.z, B0.w,
                                 B1.x, B1.y, B1.z, B1.w,
                                 Cv.x, Cv.y, Cv.z, Cv.w};
            const float ff[8] = {f0.x, f0.y, f0.z, f0.w,
                                 f1.x, f1.y, f1.z, f1.w};
#pragma unroll
            for (int dx = 0; dx < 9; ++dx)
#pragma unroll
                for (int j = 0; j < XT; ++j)
                    acc[dx][j] += ff[j] * s[dx + j];
        }
        // E/F: own LDS reads consumed; protect buf from iter k+1's stage
        if (k + 1 < NCHUNK) {
            asm volatile("s_waitcnt lgkmcnt(0)" ::: "memory");
            asm volatile("s_barrier" ::: "memory");
        }
    }

    // ---- epilogue ----
    const float scale = 1.0f / (float)C;
    const int dy = d0 + w;
    const int yOut = y0 + yi;
#pragma unroll
    for (int dx = 0; dx < 9; ++dx) {
        const int tc = dy * 9 + dx;
        float* op = &out[((b * 81 + tc) * H + yOut) * W + x0];
        float4 o0, o1;
        o0.x = acc[dx][0] * scale;
        o0.y = acc[dx][1] * scale;
        o0.z = acc[dx][2] * scale;
        o0.w = acc[dx][3] * scale;
        o1.x = acc[dx][4] * scale;
        o1.y = acc[dx][5] * scale;
        o1.z = acc[dx][6] * scale;
        o1.w = acc[dx][7] * scale;
        *(float4*)op       = o0;
        *(float4*)(op + 4) = o1;
    }
}

extern "C" void kernel_launch(void* const* d_in, const int* in_sizes, int n_in,
                              void* d_out, int out_size, void* d_ws, size_t ws_size,
                              hipStream_t stream) {
    const float* first  = (const float*)d_in[0];
    const float* second = (const float*)d_in[1];
    float* out = (float*)d_out;

    dim3 grid(B * (H / YB) * 3);   // 768 blocks = 8 XCDs x 96 = 3 per CU
    dim3 block(NTHR);              // 192 threads = 3 waves
    ModuleCorrelation_41970420416706_kernel<<<grid, block, 0, stream>>>(first, second, out);
}

// Round 4
// 185.623 us; speedup vs baseline: 2.0655x; 1.0510x over previous
//
#include <hip/hip_runtime.h>

// PWC-Net correlation: out[b, dy*9+dx, y, x] =
//   (1/C) * sum_c first[b,c,y,x] * second[b,c, y+dy-4, x+dx-4]  (zero-padded)
// B=8, C=128, H=W=128.
//
// Round 9: discriminate the staging wall. R0/R1/R3 all ran 120 DMA
// instrs/CU-chunk and all landed at ~5 TB/s effective staging (~57
// cyc/instr/CU) regardless of occupancy (18 vs 9 waves/CU) and sync
// (drain vs counted). This round halves the DMA *instruction* count at
// constant bytes: full-wave 1KB pair-DMAs (2 rows each), 20 instrs/block
// (was 40). Rows stride-128 with pairs contiguous; pads only between
// c-slabs. Edge y: each pair clamps its global start row to [0,H-2] and
// shifts its LDS dest row by the same amount -> every written LDS row
// holds correct data (double-writes identical, benign); OOB rows never
// written, prologue-zeroed once. DMA counts stay uniform (w0:8, w1/2:6)
// so counted vmcnt stays exact. Compute/epilogue/sync = R3.
// Prediction: instr-rate wall -> 62-72us; byte wall -> unchanged ~92.

#define B  8
#define C  128
#define H  128
#define W  128
#define CC 4
#define YB 4
#define XT 8
#define NTHR 192
#define NCHUNK (C / CC)        // 32
#define SROWS 6                // second rows per dy-group (yi 0..3 + w 0..2)
#define WF (4 * W + 8)         // sFirst c-slab stride (4 rows + 32B pad)
#define WS (6 * W + 8)         // sSec   c-slab stride (6 rows + 32B pad)
#define CHSTRIDE (CC * H * W)  // 65536 floats per chunk step

typedef const void __attribute__((address_space(1)))* gvp;
typedef void __attribute__((address_space(3)))* lvp;

__device__ __forceinline__ void dma16(const float* g, float* l) {
    __builtin_amdgcn_global_load_lds((gvp)g, (lvp)l, 16, 0, 0);
}

__global__ __launch_bounds__(NTHR) __attribute__((amdgpu_waves_per_eu(3)))
void ModuleCorrelation_41970420416706_kernel(const float* __restrict__ first,
                                             const float* __restrict__ second,
                                             float* __restrict__ out) {
    __shared__ __align__(16) float sFirst[2][CC][WF];   // 16.25 KiB
    __shared__ __align__(16) float sSec[2][CC][WS];     // 24.25 KiB

    // ---- XCD swizzle: phys blocks round-robin XCDs; XCD k gets batch b=k ----
    const int phys = blockIdx.x;
    const int li   = (phys & 7) * 96 + (phys >> 3);   // 768 = 8*96, bijective
    const int b    = li / 96;
    const int rem  = li - b * 96;
    const int y0   = (rem / 3) * YB;
    const int dg   = rem - (rem / 3) * 3;    // dg fastest: siblings adjacent
    const int d0   = dg * 3;                 // dy group base: 0, 3, 6
    const int base = y0 + d0 - 4;            // global row of sSec rr=0

    const int t    = threadIdx.x;
    const int w    = t >> 6;                 // wave = dy - d0, in [0,3)
    const int lane = t & 63;
    const int yi   = lane >> 4;              // 0..3
    const int xt   = lane & 15;              // 0..15
    const int x0   = xt * XT;                // 0,8,...,120

    const float* firstB  = first  + (size_t)b * C * H * W;
    const float* secondB = second + (size_t)b * C * H * W;

    // ---- pair-DMA geometry (block-uniform): pair p nominally covers global
    //      rows g=base+2p, g+1 -> LDS rows 2p, 2p+1. Clamp g to [0,H-2] and
    //      shift the LDS dest by the same amount: written rows always hold
    //      correct in-bounds data; OOB rows are never written. ----
    int gs[3], dr[3];
#pragma unroll
    for (int p = 0; p < 3; ++p) {
        const int g  = base + 2 * p;
        const int gc = g < 0 ? 0 : (g > H - 2 ? H - 2 : g);
        gs[p] = gc;
        dr[p] = gc - base;                   // dest row in [0, 4]
    }

    // ---- staging: 20 full-wave 1KB DMAs per chunk.
    //      w0: first (2 per c: rows y0..y0+1, y0+2..y0+3);
    //      w1: second c=0,1 (3 pairs each); w2: second c=2,3. ----
    auto stage = [&](int buf, int chunk) {
        const int off = chunk * CHSTRIDE;
        if (w == 0) {
#pragma unroll
            for (int c = 0; c < CC; ++c) {
                dma16(firstB + off + (c * H + y0) * W + lane * 4,
                      &sFirst[buf][c][0]);
                dma16(firstB + off + (c * H + y0 + 2) * W + lane * 4,
                      &sFirst[buf][c][2 * W]);
            }
        } else {
            const int c0 = (w == 1) ? 0 : 2;
#pragma unroll
            for (int ci = 0; ci < 2; ++ci) {
                const int c = c0 + ci;
#pragma unroll
                for (int p = 0; p < 3; ++p)
                    dma16(secondB + off + (c * H + gs[p]) * W + lane * 4,
                          &sSec[buf][c][dr[p] * W]);
            }
        }
    };

    // ---- prologue: stage chunk 0; zero never-written OOB rows once ----
    stage(0, 0);
    {
        const float4 z4 = make_float4(0.f, 0.f, 0.f, 0.f);
        for (int idx = t; idx < 2 * CC * SROWS; idx += NTHR) {  // 48 rows
            const int rr = idx % SROWS;
            const int ys = base + rr;
            if (ys < 0 || ys >= H) {
                const int bf = idx / (CC * SROWS);
                const int c  = (idx / SROWS) % CC;
                float4* p4 = (float4*)&sSec[bf][c][rr * W];
                for (int x = 0; x < W / 4; ++x) p4[x] = z4;
            }
        }
    }
    asm volatile("s_waitcnt lgkmcnt(0)" ::: "memory");   // zero-stores done

    float acc[9][XT];
#pragma unroll
    for (int dx = 0; dx < 9; ++dx)
#pragma unroll
        for (int j = 0; j < XT; ++j) acc[dx][j] = 0.f;

    const bool edgeL = (xt == 0);
    const bool edgeR = (xt == 15);
    const int offA = edgeL ? 0 : x0 - 4;      // clamped aligned read, masked below
    const int offC = edgeR ? x0 + 4 : x0 + 8;
    const int fOff = yi * W + x0;
    const int sOff = (yi + w) * W;            // rr = yi + w

    for (int k = 0; k < NCHUNK; ++k) {
        const int buf = k & 1;
        // A: issue next chunk (buf^1 is free: protect barrier of k-1 passed)
        if (k + 1 < NCHUNK) {
            stage(buf ^ 1, k + 1);
            // B: wait for OWN chunk-k loads (the N just issued may remain)
            if (w == 0) asm volatile("s_waitcnt vmcnt(8)" ::: "memory");
            else        asm volatile("s_waitcnt vmcnt(6)" ::: "memory");
        } else {
            asm volatile("s_waitcnt vmcnt(0)" ::: "memory");
        }
        // C: publish — after this, ALL waves' chunk-k rows are in LDS
        asm volatile("s_barrier" ::: "memory");

        const float* sF  = &sFirst[buf][0][0];
        const float* sSb = &sSec[buf][0][0];
#pragma unroll
        for (int c = 0; c < CC; ++c) {
            const float4 f0 = *(const float4*)(sF + c * WF + fOff);
            const float4 f1 = *(const float4*)(sF + c * WF + fOff + 4);
            const float* sr = sSb + c * WS + sOff;
            float4 A        = *(const float4*)(sr + offA);
            const float4 B0 = *(const float4*)(sr + x0);
            const float4 B1 = *(const float4*)(sr + x0 + 4);
            float4 Cv       = *(const float4*)(sr + offC);
            if (edgeL) { A.x = 0.f; A.y = 0.f; A.z = 0.f; A.w = 0.f; }
            if (edgeR) { Cv.x = 0.f; Cv.y = 0.f; Cv.z = 0.f; Cv.w = 0.f; }
            const float s[16] = {A.x,  A.y,  A.z,  A.w,
                                 B0.x, B0.y, B0.z, B0.w,
                                 B1.x, B1.y, B1.z, B1.w,
                                 Cv.x, Cv.y, Cv.z, Cv.w};
            const float ff[8] = {f0.x, f0.y, f0.z, f0.w,
                                 f1.x, f1.y, f1.z, f1.w};
#pragma unroll
            for (int dx = 0; dx < 9; ++dx)
#pragma unroll
                for (int j = 0; j < XT; ++j)
                    acc[dx][j] += ff[j] * s[dx + j];
        }
        // E/F: own LDS reads consumed; protect buf from iter k+1's stage
        if (k + 1 < NCHUNK) {
            asm volatile("s_waitcnt lgkmcnt(0)" ::: "memory");
            asm volatile("s_barrier" ::: "memory");
        }
    }

    // ---- epilogue ----
    const float scale = 1.0f / (float)C;
    const int dy = d0 + w;
    const int yOut = y0 + yi;
#pragma unroll
    for (int dx = 0; dx < 9; ++dx) {
        const int tc = dy * 9 + dx;
        float* op = &out[((b * 81 + tc) * H + yOut) * W + x0];
        float4 o0, o1;
        o0.x = acc[dx][0] * scale;
        o0.y = acc[dx][1] * scale;
        o0.z = acc[dx][2] * scale;
        o0.w = acc[dx][3] * scale;
        o1.x = acc[dx][4] * scale;
        o1.y = acc[dx][5] * scale;
        o1.z = acc[dx][6] * scale;
        o1.w = acc[dx][7] * scale;
        *(float4*)op       = o0;
        *(float4*)(op + 4) = o1;
    }
}

extern "C" void kernel_launch(void* const* d_in, const int* in_sizes, int n_in,
                              void* d_out, int out_size, void* d_ws, size_t ws_size,
                              hipStream_t stream) {
    const float* first  = (const float*)d_in[0];
    const float* second = (const float*)d_in[1];
    float* out = (float*)d_out;

    dim3 grid(B * (H / YB) * 3);   // 768 blocks = 8 XCDs x 96 = 3 per CU
    dim3 block(NTHR);              // 192 threads = 3 waves
    ModuleCorrelation_41970420416706_kernel<<<grid, block, 0, stream>>>(first, second, out);
}